// Round 4
// baseline (167.937 us; speedup 1.0000x reference)
//
#include <hip/hip_runtime.h>

#define STEPS 32768
#define DIO 63
#define HSZ 256
#define NL 6
#define BM 64
#define THREADS 512

// fragment-ordered weights in d_ws (A-role fragments; lane l = feature row l&15, k-slice (l>>4)*8)
#define NBGF  (NL * 3 * 16 * 8 * 64 * 8)   // [l][g][nb=16][kk=8][lane][e], bf16, pre-scaled by log2e factors
#define NBIAS (NL * 768)                    // fused (b_ih+b_hh)*scale, f32, [l][g][256]
#define NBINF (16 * 2 * 64 * 8)             // W_in  [nb][kk][lane][e], K padded 63->64
#define NBFCF (4 * 8 * 64 * 8)              // W_fc  [nb][kk][lane][e]

typedef __bf16 bf16_8 __attribute__((ext_vector_type(8)));
typedef __bf16 bf16_4 __attribute__((ext_vector_type(4)));
typedef float f32x4 __attribute__((ext_vector_type(4)));

#define LOG2E  1.4426950408889634f
#define LOG2E2 2.8853900817779268f

__device__ __forceinline__ unsigned short f2bf(float f) {
    unsigned int u = __float_as_uint(f);
    u = u + 0x7fffu + ((u >> 16) & 1u);   // RNE
    return (unsigned short)(u >> 16);
}

// ---- weight prep: fp32 -> bf16, MFMA A-fragment order, log2e pre-scaling ----
__global__ void prep_kernel(const float* __restrict__ W_in,
                            const float* __restrict__ W_ih,
                            const float* __restrict__ b_ih,
                            const float* __restrict__ b_hh,
                            const float* __restrict__ W_fc,
                            unsigned short* __restrict__ Bg,
                            float* __restrict__ bias,
                            unsigned short* __restrict__ Bin,
                            unsigned short* __restrict__ Bfc) {
    int idx = blockIdx.x * 256 + threadIdx.x;
    if (idx < NBGF) {
        int e    = idx & 7;
        int lane = (idx >> 3) & 63;
        int kk   = (idx >> 9) & 7;
        int nb   = (idx >> 12) & 15;
        int lg   = idx >> 16;          // 0..17
        int l = lg / 3, g = lg % 3;
        int f = nb * 16 + (lane & 15);
        int k = kk * 32 + (lane >> 4) * 8 + e;
        int r = f + (g == 0 ? 0 : (g == 1 ? 512 : 768));   // torch gate order i,f,g,o; f dead
        float sc = (g == 1) ? LOG2E2 : LOG2E;              // exp2-ready gates
        Bg[idx] = f2bf(W_ih[((size_t)l * 1024 + r) * HSZ + k] * sc);
        return;
    }
    idx -= NBGF;
    if (idx < NBIAS) {
        int j = idx % 768, l = idx / 768;
        int g = j >> 8;
        int r = (j < 256) ? j : j + 256;
        float sc = (g == 1) ? LOG2E2 : LOG2E;
        bias[idx] = (b_ih[l * 1024 + r] + b_hh[l * 1024 + r]) * sc;
        return;
    }
    idx -= NBIAS;
    if (idx < NBINF) {
        int e = idx & 7, lane = (idx >> 3) & 63, kk = (idx >> 9) & 1, nb = idx >> 10;
        int f = nb * 16 + (lane & 15);
        int k = kk * 32 + (lane >> 4) * 8 + e;
        Bin[idx] = (k < DIO) ? f2bf(W_in[f * DIO + k]) : (unsigned short)0;
        return;
    }
    idx -= NBINF;
    if (idx < NBFCF) {
        int e = idx & 7, lane = (idx >> 3) & 63, kk = (idx >> 9) & 7, nb = idx >> 12;
        int f = nb * 16 + (lane & 15);
        int k = kk * 32 + (lane >> 4) * 8 + e;
        Bfc[idx] = (f < DIO) ? f2bf(W_fc[f * HSZ + k]) : (unsigned short)0;
    }
}

// ---- fused MLP-ized LSTM, operand-swapped (gates^T = W * h^T) ----
// h_lds layout [kk=8][lq=4][s=64][e=8] bf16: B-frag read = 1 base VGPR + immediates,
// contiguous 256B per 16-lane group -> conflict-free, no swizzle.
__global__ __launch_bounds__(THREADS, 2) void rnn_fused(
    const float* __restrict__ inp, const float* __restrict__ b_in,
    const float* __restrict__ b_fc,
    const unsigned short* __restrict__ Bg, const float* __restrict__ bias,
    const unsigned short* __restrict__ Bin, const unsigned short* __restrict__ Bfc,
    float* __restrict__ out) {
    __shared__ __align__(16) unsigned short h_lds[8 * 4 * 64 * 8];    // 32KB
    __shared__ __align__(16) unsigned short in_lds[2 * 4 * 64 * 8];   //  8KB

    const int tid = threadIdx.x;
    const int lane = tid & 63;
    const int l15 = lane & 15;
    const int lq = lane >> 4;
    const int wid = tid >> 6;
    const int row0 = blockIdx.x * BM;

    // one LDS read-base for ALL B-fragment reads (gate GEMMs, input GEMM, FC)
    const int rdBase = lq * 1024 + l15 * 16;
    // one LDS write-base for all epilogue b64 writes
    const int wrBase = wid * 4096 + (lq >> 1) * 1024 + l15 * 16 + (lq & 1) * 8;

    // ---- stage input tile (64 x 63 fp32 -> bf16, K padded to 64), layout [kk][lq][s][e] ----
    for (int idx = tid; idx < BM * 64; idx += THREADS) {
        int s = idx >> 6, k = idx & 63;
        float v = (k < DIO) ? inp[(size_t)(row0 + s) * DIO + k] : 0.f;
        int off = (k >> 5) * 4096 + ((k >> 3) & 3) * 1024 + s * 16 + (k & 7) * 2;
        *(unsigned short*)((char*)in_lds + off) = f2bf(v);
    }
    __syncthreads();

    // ---- input GEMM: x^T = W_in * inp^T + b_in -> h_lds ----
    {
        f32x4 acc[2][4];
#pragma unroll
        for (int m = 0; m < 2; ++m) {
            f32x4 b4 = *(const f32x4*)(b_in + wid * 32 + m * 16 + lq * 4);
#pragma unroll
            for (int n = 0; n < 4; ++n) acc[m][n] = b4;
        }
        const bf16_8* __restrict__ pA = (const bf16_8*)Bin;
#pragma unroll
        for (int kk = 0; kk < 2; ++kk) {
            bf16_8 a[2], b[4];
#pragma unroll
            for (int m = 0; m < 2; ++m) a[m] = pA[((wid * 2 + m) * 2 + kk) * 64 + lane];
#pragma unroll
            for (int n = 0; n < 4; ++n)
                b[n] = *(const bf16_8*)((const char*)in_lds + rdBase + kk * 4096 + n * 256);
#pragma unroll
            for (int m = 0; m < 2; ++m)
#pragma unroll
                for (int n = 0; n < 4; ++n)
                    acc[m][n] = __builtin_amdgcn_mfma_f32_16x16x32_bf16(a[m], b[n], acc[m][n], 0, 0, 0);
        }
#pragma unroll
        for (int m = 0; m < 2; ++m)
#pragma unroll
            for (int n = 0; n < 4; ++n) {
                bf16_4 hv;
#pragma unroll
                for (int r = 0; r < 4; ++r) hv[r] = (__bf16)acc[m][n][r];
                *(bf16_4*)((char*)h_lds + wrBase + m * 2048 + n * 256) = hv;
            }
    }
    __syncthreads();

    // ---- 6 layers x 3 gates (i,g,o; f-gate dead since c_prev==0) ----
    for (int l = 0; l < NL; ++l) {
        f32x4 tt[2][4];
#pragma unroll
        for (int g = 0; g < 3; ++g) {
            const bf16_8* __restrict__ pA = (const bf16_8*)(Bg + ((size_t)(l * 3 + g) << 16));
            const float* __restrict__ bg = bias + (l * 3 + g) * 256;
            f32x4 acc[2][4];
#pragma unroll
            for (int m = 0; m < 2; ++m) {
                f32x4 b4 = *(const f32x4*)(bg + wid * 32 + m * 16 + lq * 4);
#pragma unroll
                for (int n = 0; n < 4; ++n) acc[m][n] = b4;
            }
#pragma unroll
            for (int kk = 0; kk < 8; ++kk) {
                bf16_8 a[2], b[4];
#pragma unroll
                for (int m = 0; m < 2; ++m) a[m] = pA[((wid * 2 + m) * 8 + kk) * 64 + lane];
#pragma unroll
                for (int n = 0; n < 4; ++n)
                    b[n] = *(const bf16_8*)((const char*)h_lds + rdBase + kk * 4096 + n * 256);
#pragma unroll
                for (int m = 0; m < 2; ++m)
#pragma unroll
                    for (int n = 0; n < 4; ++n)
                        acc[m][n] = __builtin_amdgcn_mfma_f32_16x16x32_bf16(a[m], b[n], acc[m][n], 0, 0, 0);
            }
            // activations (gates pre-scaled by log2e):
            //  g0: tt = 2^i' (= e^i);  g1: c = ei(eg-1)/((1+ei)(1+eg)); tt = tanh(c) Pade(5,4)
            //  g2: h = tt * eo/(1+eo)
#pragma unroll
            for (int m = 0; m < 2; ++m)
#pragma unroll
                for (int n = 0; n < 4; ++n)
#pragma unroll
                    for (int r = 0; r < 4; ++r) {
                        float v = acc[m][n][r];
                        if (g == 0) {
                            tt[m][n][r] = __builtin_amdgcn_exp2f(fminf(v, 34.f));
                        } else if (g == 1) {
                            float eg = __builtin_amdgcn_exp2f(fminf(v, 60.f));
                            float ei = tt[m][n][r];
                            float c = ei * (eg - 1.f) *
                                      __builtin_amdgcn_rcpf((1.f + ei) * (1.f + eg));
                            float z = c * c;
                            float tn = fmaf(z + 105.f, z, 945.f);
                            float td = fmaf(fmaf(15.f, z, 420.f), z, 945.f);
                            tt[m][n][r] = c * tn * __builtin_amdgcn_rcpf(td);
                        } else {
                            float eo = __builtin_amdgcn_exp2f(fminf(v, 34.f));
                            tt[m][n][r] = tt[m][n][r] * eo * __builtin_amdgcn_rcpf(1.f + eo);
                        }
                    }
        }
        __syncthreads();   // all waves done reading h_lds
#pragma unroll
        for (int m = 0; m < 2; ++m)
#pragma unroll
            for (int n = 0; n < 4; ++n) {
                bf16_4 hv;
#pragma unroll
                for (int r = 0; r < 4; ++r) hv[r] = (__bf16)tt[m][n][r];
                *(bf16_4*)((char*)h_lds + wrBase + m * 2048 + n * 256) = hv;
            }
        __syncthreads();
    }

    // ---- final GEMM: out^T = W_fc * h^T + b_fc ----
    {
        const int fm = wid >> 1;          // feature tile 0..3
        const int sn0 = (wid & 1) * 2;    // step tiles sn0, sn0+1
        f32x4 o4[2];
#pragma unroll
        for (int n = 0; n < 2; ++n) o4[n] = (f32x4){0.f, 0.f, 0.f, 0.f};
        const bf16_8* __restrict__ pA = (const bf16_8*)Bfc;
#pragma unroll
        for (int kk = 0; kk < 8; ++kk) {
            bf16_8 a = pA[(fm * 8 + kk) * 64 + lane];
#pragma unroll
            for (int n = 0; n < 2; ++n) {
                bf16_8 b = *(const bf16_8*)((const char*)h_lds + rdBase + kk * 4096 + (sn0 + n) * 256);
                o4[n] = __builtin_amdgcn_mfma_f32_16x16x32_bf16(a, b, o4[n], 0, 0, 0);
            }
        }
#pragma unroll
        for (int n = 0; n < 2; ++n) {
            int s = row0 + (sn0 + n) * 16 + l15;
#pragma unroll
            for (int r = 0; r < 4; ++r) {
                int f = fm * 16 + lq * 4 + r;
                if (f < DIO) out[(size_t)s * DIO + f] = o4[n][r] + b_fc[f];
            }
        }
    }
}

extern "C" void kernel_launch(void* const* d_in, const int* in_sizes, int n_in,
                              void* d_out, int out_size, void* d_ws, size_t ws_size,
                              hipStream_t stream) {
    const float* inputs = (const float*)d_in[0];
    const float* W_in   = (const float*)d_in[1];
    const float* b_in   = (const float*)d_in[2];
    const float* W_ih   = (const float*)d_in[3];
    // d_in[4] = W_hh: unused (h_prev == 0 every step)
    const float* b_ih   = (const float*)d_in[5];
    const float* b_hh   = (const float*)d_in[6];
    const float* W_fc   = (const float*)d_in[7];
    const float* b_fc   = (const float*)d_in[8];

    unsigned short* Bg  = (unsigned short*)d_ws;
    float* bias         = (float*)((char*)d_ws + (size_t)NBGF * 2);
    unsigned short* Bin = (unsigned short*)((char*)bias + (size_t)NBIAS * 4);
    unsigned short* Bfc = Bin + NBINF;

    int total = NBGF + NBIAS + NBINF + NBFCF;
    prep_kernel<<<(total + 255) / 256, 256, 0, stream>>>(W_in, W_ih, b_ih, b_hh, W_fc,
                                                         Bg, bias, Bin, Bfc);
    rnn_fused<<<STEPS / BM, THREADS, 0, stream>>>(inputs, b_in, b_fc, Bg, bias, Bin, Bfc,
                                                  (float*)d_out);
}